// Round 10
// baseline (196.601 us; speedup 1.0000x reference)
//
#include <hip/hip_runtime.h>
#include <hip/hip_bf16.h>
#include <stdint.h>

#define DEV __device__ __forceinline__

typedef __attribute__((ext_vector_type(8))) short   s16x8;
typedef __attribute__((ext_vector_type(8))) __bf16  bf16x8;
typedef __attribute__((ext_vector_type(4))) float   f32x4;

static constexpr int BATCH = 8;
static constexpr int DIM   = 512;
static constexpr int HEADS = 8;
static constexpr int HD    = 64;
static constexpr int HW    = 4096;
static constexpr int CQKV  = 1536;
static constexpr int NSPLIT = 8;

DEV void gload16(const void* g, void* l) {
  __builtin_amdgcn_global_load_lds(
      (const __attribute__((address_space(1))) void*)g,
      (__attribute__((address_space(3))) void*)l,
      16, 0, 0);
}

DEV f32x4 mfma16x32(s16x8 a, s16x8 b, f32x4 c) {
  return __builtin_amdgcn_mfma_f32_16x16x32_bf16(
      __builtin_bit_cast(bf16x8, a), __builtin_bit_cast(bf16x8, b), c, 0, 0, 0);
}

DEV float b2f(short x) {
  unsigned u = (unsigned)(unsigned short)x << 16;
  return __uint_as_float(u);
}
DEV short f2b(float f) { return __builtin_bit_cast(short, __float2bfloat16(f)); }

// =====================================================================
// 1) MERGED: transpose_x (z<8) + weight convert (z==8)
// =====================================================================
__global__ __launch_bounds__(256) void trx_prep(
    const float* __restrict__ x, __hip_bfloat16* __restrict__ XT,
    const float* __restrict__ wq, const float* __restrict__ wk,
    const float* __restrict__ wv, const float* __restrict__ wp,
    __hip_bfloat16* __restrict__ wqkv, __hip_bfloat16* __restrict__ wpb)
{
  const int t = threadIdx.x;
  if (blockIdx.z == 8) {
    long i0 = (((long)blockIdx.y * 64 + blockIdx.x) * 256 + t) * 8;
    const float* src;
    __hip_bfloat16* dst;
    long off;
    if (i0 < (long)CQKV * DIM) {
      int r = (int)(i0 >> 9);
      src = (r < 512) ? wq : (r < 1024) ? wk : wv;
      off = (long)(r & 511) * DIM + (i0 & 511);
      dst = wqkv + i0;
    } else {
      long j0 = i0 - (long)CQKV * DIM;
      src = wp; off = j0; dst = wpb + j0;
    }
    float4 a = *(const float4*)&src[off];
    float4 b = *(const float4*)&src[off + 4];
    s16x8 v;
    v[0] = f2b(a.x); v[1] = f2b(a.y); v[2] = f2b(a.z); v[3] = f2b(a.w);
    v[4] = f2b(b.x); v[5] = f2b(b.y); v[6] = f2b(b.z); v[7] = f2b(b.w);
    *(s16x8*)dst = v;
    return;
  }
  __shared__ float tile[64 * 65];
  const int n0 = blockIdx.x * 64, c0 = blockIdx.y * 64, b = blockIdx.z;
#pragma unroll
  for (int i = 0; i < 16; ++i) {
    int f = i * 256 + t; int ci = f >> 6, nj = f & 63;
    tile[ci * 65 + nj] = x[((long)b * DIM + c0 + ci) * HW + n0 + nj];
  }
  __syncthreads();
#pragma unroll
  for (int i = 0; i < 16; ++i) {
    int f = i * 256 + t; int ni = f >> 6, cj = f & 63;
    XT[((long)b * HW + n0 + ni) * DIM + c0 + cj] = __float2bfloat16(tile[cj * 65 + ni]);
  }
}

// =====================================================================
// 3) gemm_bt: 2-phase 128x128, BK=64, T2-swizzled LDS (R1-proven, 69.6us)
//    + T1 XCD-aware block swizzle: flat grid, swz=(lid%8)*(nwg/8)+lid/8
//    -> each XCD owns one batch (XT slice L2-resident per XCD) and
//    consecutive blocks within an XCD share the A (weight) panel.
// =====================================================================
__global__ __launch_bounds__(256) void gemm_bt(
    const __hip_bfloat16* __restrict__ A,
    const __hip_bfloat16* __restrict__ Bt,
    __hip_bfloat16* __restrict__ Cout,
    int NXT, int MT, int K, int nwg,       // n-tiles, m-tiles, K, total blocks
    int N, long bt_bstride, long c_bstride)
{
  const int lid = blockIdx.x;
  const int swz = (lid & 7) * (nwg >> 3) + (lid >> 3);
  const int nx = swz % NXT;
  const int my = (swz / NXT) % MT;
  const int b  = swz / (NXT * MT);

  __shared__ __hip_bfloat16 ldsA[128 * 64];
  __shared__ __hip_bfloat16 ldsB[128 * 64];
  const int t = threadIdx.x, w = t >> 6, l = t & 63;
  const int m0 = my * 128, n0 = nx * 128;
  const int wr = w >> 1, wc = w & 1;
  const __hip_bfloat16* Bb = Bt + (long)b * bt_bstride;

  f32x4 acc[4][4] = {};

  for (int k0 = 0; k0 < K; k0 += 64) {
#pragma unroll
    for (int i = 0; i < 4; ++i) {
      int r = w * 32 + i * 8 + (l >> 3);
      int c = (l & 7) ^ (r & 7);
      gload16(A  + (long)(m0 + r) * K + k0 + c * 8, &ldsA[w * 2048 + i * 512]);
      gload16(Bb + (long)(n0 + r) * K + k0 + c * 8, &ldsB[w * 2048 + i * 512]);
    }
    __syncthreads();
#pragma unroll
    for (int kk = 0; kk < 64; kk += 32) {
      s16x8 af[4], bfr[4];
#pragma unroll
      for (int mi = 0; mi < 4; ++mi) {
        int ar = wr * 64 + mi * 16 + (l & 15);
        int col = (kk + (l >> 4) * 8) ^ ((ar & 7) << 3);
        af[mi] = *(const s16x8*)&ldsA[ar * 64 + col];
      }
#pragma unroll
      for (int ni = 0; ni < 4; ++ni) {
        int br = wc * 64 + ni * 16 + (l & 15);
        int col = (kk + (l >> 4) * 8) ^ ((br & 7) << 3);
        bfr[ni] = *(const s16x8*)&ldsB[br * 64 + col];
      }
#pragma unroll
      for (int mi = 0; mi < 4; ++mi)
#pragma unroll
        for (int ni = 0; ni < 4; ++ni)
          acc[mi][ni] = mfma16x32(af[mi], bfr[ni], acc[mi][ni]);
    }
    __syncthreads();
  }

  const int row0 = m0 + wr * 64, col0 = n0 + wc * 64;
#pragma unroll
  for (int mi = 0; mi < 4; ++mi)
#pragma unroll
    for (int ni = 0; ni < 4; ++ni)
#pragma unroll
      for (int j = 0; j < 4; ++j) {
        long rr = row0 + mi * 16 + (l >> 4) * 4 + j;
        long cc = col0 + ni * 16 + (l & 15);
        Cout[(long)b * c_bstride + rr * N + cc] = __float2bfloat16(acc[mi][ni][j]);
      }
}

// =====================================================================
// 3b) gemm_bt8: 256x256 8-phase (proj, fp32 out) + T1 XCD swizzle
// =====================================================================
__global__ __launch_bounds__(512, 2) void gemm_bt8(
    const __hip_bfloat16* __restrict__ A,
    const __hip_bfloat16* __restrict__ Bt,
    float* __restrict__ Cout,
    int NXT, int MT, int K, int nwg,
    int N, long bt_bstride, long c_bstride)
{
  const int lid = blockIdx.x;
  const int swz = (lid & 7) * (nwg >> 3) + (lid >> 3);
  const int nx = swz % NXT;
  const int my = (swz / NXT) % MT;
  const int b  = swz / (NXT * MT);

  __shared__ __hip_bfloat16 lds[65536];
  const int t = threadIdx.x, w = t >> 6, l = t & 63;
  const int wm = w >> 2, wn = w & 3;
  const int m0 = my * 256, n0 = nx * 256;
  const __hip_bfloat16* Bb = Bt + (long)b * bt_bstride;

  const int rl = t >> 3;
  const int ch = ((t & 7) ^ (rl & 7)) * 8;
  const int fr = l & 15, fk = (l >> 4) * 8;
  const int fswz = (l & 7) << 3;

  auto stageA = [&](int p, int h, int u) {
    const __hip_bfloat16* src = A + (long)(m0 + h * 64 + rl) * K + u * 64 + ch;
    __hip_bfloat16* dst = lds + p * 16384 + h * 8192 + w * 512;
    gload16(src, dst);
    gload16(src + 128l * K, dst + 4096);
  };
  auto stageB = [&](int p, int hb, int u) {
    const __hip_bfloat16* src = Bb + (long)(n0 + hb * 128 + rl) * K + u * 64 + ch;
    __hip_bfloat16* dst = lds + 32768 + p * 16384 + hb * 8192 + w * 512;
    gload16(src, dst);
    gload16(src + 64l * K, dst + 4096);
  };

  f32x4 acc[8][4] = {};
  const int NT = K >> 6;

  stageB(0, 0, 0); stageB(0, 1, 0); stageA(0, 0, 0); stageA(0, 1, 0);
  stageB(1, 0, 1); stageB(1, 1, 1); stageA(1, 0, 1);
  asm volatile("s_waitcnt vmcnt(6)" ::: "memory");
  __builtin_amdgcn_s_barrier();

  for (int u = 0; u < NT; ++u) {
    const int p = u & 1;
    const __hip_bfloat16* lA = lds + p * 16384 + wm * 4096;
    const __hip_bfloat16* lB = lds + 32768 + p * 16384 + (wn >> 1) * 8192
                             + (wn & 1) * 4096;
    s16x8 bfr[2][4];
#pragma unroll
    for (int q = 0; q < 4; ++q) {
      s16x8 afr[2][2];
#pragma unroll
      for (int kk = 0; kk < 2; ++kk)
#pragma unroll
        for (int mi = 0; mi < 2; ++mi)
          afr[kk][mi] = *(const s16x8*)&lA[(q >> 1) * 8192
              + ((q & 1) * 32 + mi * 16 + fr) * 64 + ((kk * 32 + fk) ^ fswz)];
      if (q == 0) {
#pragma unroll
        for (int kk = 0; kk < 2; ++kk)
#pragma unroll
          for (int ni = 0; ni < 4; ++ni)
            bfr[kk][ni] = *(const s16x8*)&lB[(ni * 16 + fr) * 64
                + ((kk * 32 + fk) ^ fswz)];
      }
      if (q == 0)      { if (u + 1 < NT) stageA(p ^ 1, 1, u + 1); }
      else if (q == 1) { if (u + 2 < NT) stageB(p, 0, u + 2); }
      else if (q == 2) { if (u + 2 < NT) stageB(p, 1, u + 2); }
      else {
        if (u + 2 < NT) stageA(p, 0, u + 2);
        if (u == NT - 2) asm volatile("s_waitcnt vmcnt(0)" ::: "memory");
        else             asm volatile("s_waitcnt vmcnt(6)" ::: "memory");
      }
      __builtin_amdgcn_s_barrier();
      asm volatile("s_waitcnt lgkmcnt(0)" ::: "memory");
      __builtin_amdgcn_sched_barrier(0);
      __builtin_amdgcn_s_setprio(1);
#pragma unroll
      for (int kk = 0; kk < 2; ++kk)
#pragma unroll
        for (int mi = 0; mi < 2; ++mi)
#pragma unroll
          for (int ni = 0; ni < 4; ++ni)
            acc[q * 2 + mi][ni] = mfma16x32(afr[kk][mi], bfr[kk][ni],
                                            acc[q * 2 + mi][ni]);
      __builtin_amdgcn_s_setprio(0);
      __builtin_amdgcn_s_barrier();
    }
  }

  const int row0 = m0 + wm * 128, col0 = n0 + wn * 64;
#pragma unroll
  for (int mi = 0; mi < 8; ++mi)
#pragma unroll
    for (int ni = 0; ni < 4; ++ni)
#pragma unroll
      for (int j = 0; j < 4; ++j) {
        long rr = row0 + mi * 16 + (l >> 4) * 4 + j;
        long cc = col0 + ni * 16 + fr;
        Cout[(long)b * c_bstride + rr * N + cc] = acc[mi][ni][j];
      }
}

// =====================================================================
// 4) depthwise 3x3, IN-PLACE on P; q/k emit rnorm
// =====================================================================
__global__ __launch_bounds__(256) void dwconv(
    __hip_bfloat16* __restrict__ P,
    const float* __restrict__ dwq, const float* __restrict__ dwk,
    const float* __restrict__ dwv, float* __restrict__ rnorm)
{
  __shared__ float pl[66 * 67];
  __shared__ float red4[4];
  const int c = blockIdx.x, b = blockIdx.y, t = threadIdx.x;
  const int w = t >> 6, l = t & 63;

  if (t < 66) { pl[t] = 0.f; pl[65 * 67 + t] = 0.f; }
  if (t >= 128 && t < 192) { pl[(t - 127) * 67] = 0.f; }
  if (t >= 192)            { pl[(t - 191) * 67 + 65] = 0.f; }

  const long base = ((long)b * CQKV + c) * HW;
  const int y = t >> 2, x0 = (t & 3) * 16;
  s16x8 v0 = *(const s16x8*)&P[base + t * 16];
  s16x8 v1 = *(const s16x8*)&P[base + t * 16 + 8];
#pragma unroll
  for (int j = 0; j < 8; ++j) {
    pl[(y + 1) * 67 + x0 + 1 + j] = b2f(v0[j]);
    pl[(y + 1) * 67 + x0 + 9 + j] = b2f(v1[j]);
  }
  __syncthreads();

  const int qkv = c >> 9, cc = c & 511;
  const float* dw = ((qkv == 0) ? dwq : (qkv == 1) ? dwk : dwv) + (long)cc * 9;
  const float w0 = dw[0], w1 = dw[1], w2 = dw[2], w3 = dw[3], w4 = dw[4],
              w5 = dw[5], w6 = dw[6], w7 = dw[7], w8 = dw[8];

  const float* r0 = &pl[y * 67 + x0];
  float outv[16];
  float ss = 0.f;
#pragma unroll
  for (int j = 0; j < 16; ++j) {
    float s = w0 * r0[j]       + w1 * r0[j + 1]   + w2 * r0[j + 2]
            + w3 * r0[j + 67]  + w4 * r0[j + 68]  + w5 * r0[j + 69]
            + w6 * r0[j + 134] + w7 * r0[j + 135] + w8 * r0[j + 136];
    outv[j] = s;
    ss += s * s;
  }
  s16x8 o0, o1;
#pragma unroll
  for (int j = 0; j < 8; ++j) { o0[j] = f2b(outv[j]); o1[j] = f2b(outv[j + 8]); }
  *(s16x8*)&P[base + t * 16]     = o0;
  *(s16x8*)&P[base + t * 16 + 8] = o1;

  if (qkv < 2) {
#pragma unroll
    for (int off = 32; off; off >>= 1) ss += __shfl_down(ss, off);
    if (l == 0) red4[w] = ss;
    __syncthreads();
    if (t == 0)
      rnorm[(long)b * 1024 + qkv * 512 + cc] =
          1.f / fmaxf(sqrtf(red4[0] + red4[1] + red4[2] + red4[3]), 1e-12f);
  }
}

// =====================================================================
// 5) V slice of P -> VT [b][h][4096][64] bf16
// =====================================================================
__global__ __launch_bounds__(256) void transpose_v(
    const __hip_bfloat16* __restrict__ P, __hip_bfloat16* __restrict__ VT)
{
  __shared__ __hip_bfloat16 tile[64 * 65];
  const int n0 = blockIdx.x * 64, h = blockIdx.y, b = blockIdx.z;
  const int t = threadIdx.x;
#pragma unroll
  for (int i = 0; i < 16; ++i) {
    int f = i * 256 + t; int ei = f >> 6, nj = f & 63;
    tile[ei * 65 + nj] = P[((long)b * CQKV + 1024 + h * HD + ei) * HW + n0 + nj];
  }
  __syncthreads();
#pragma unroll
  for (int i = 0; i < 16; ++i) {
    int f = i * 256 + t; int ni = f >> 6, ej = f & 63;
    VT[(((long)b * HEADS + h) * HW + n0 + ni) * HD + ej] = tile[ej * 65 + ni];
  }
}

// =====================================================================
// 6a) attention score partials, split-K over hw
// =====================================================================
__global__ __launch_bounds__(256) void attn_partial(__hip_bfloat16* __restrict__ P)
{
  __shared__ __hip_bfloat16 ldsQ[64 * 128];
  __shared__ __hip_bfloat16 ldsK[64 * 128];
  const int t = threadIdx.x, w = t >> 6, l = t & 63;
  const int sp = blockIdx.x, h = blockIdx.y, b = blockIdx.z;
  const int wr = w >> 1, wc = w & 1;

  const long qbase = ((long)b * CQKV + h * HD) * HW;
  const long kbase = ((long)b * CQKV + 512 + h * HD) * HW;

  f32x4 acc[2][2] = {};

  const int kend = sp * 512 + 512;
  for (int k0 = sp * 512; k0 < kend; k0 += 128) {
#pragma unroll
    for (int i = 0; i < 4; ++i) {
      int r = w * 16 + i * 4 + (l >> 4);
      int c = (l & 15) ^ (r & 7);
      gload16(P + qbase + (long)r * HW + k0 + c * 8, &ldsQ[w * 2048 + i * 512]);
      gload16(P + kbase + (long)r * HW + k0 + c * 8, &ldsK[w * 2048 + i * 512]);
    }
    __syncthreads();
#pragma unroll
    for (int kk = 0; kk < 128; kk += 32) {
      s16x8 af[2], bfr[2];
#pragma unroll
      for (int mi = 0; mi < 2; ++mi) {
        int ar = wr * 32 + mi * 16 + (l & 15);
        int col = (kk + (l >> 4) * 8) ^ ((ar & 7) << 3);
        af[mi] = *(const s16x8*)&ldsQ[ar * 128 + col];
      }
#pragma unroll
      for (int ni = 0; ni < 2; ++ni) {
        int br = wc * 32 + ni * 16 + (l & 15);
        int col = (kk + (l >> 4) * 8) ^ ((br & 7) << 3);
        bfr[ni] = *(const s16x8*)&ldsK[br * 128 + col];
      }
#pragma unroll
      for (int mi = 0; mi < 2; ++mi)
#pragma unroll
        for (int ni = 0; ni < 2; ++ni)
          acc[mi][ni] = mfma16x32(af[mi], bfr[ni], acc[mi][ni]);
    }
    __syncthreads();
  }

  float* part = (float*)((char*)P + (long)b * (CQKV * HW * 2) + (1024l * HW * 2))
              + ((long)h * NSPLIT + sp) * 4096;
#pragma unroll
  for (int mi = 0; mi < 2; ++mi)
#pragma unroll
    for (int ni = 0; ni < 2; ++ni)
#pragma unroll
      for (int j = 0; j < 4; ++j) {
        int row = wr * 32 + mi * 16 + (l >> 4) * 4 + j;
        int col = wc * 32 + ni * 16 + (l & 15);
        part[row * 64 + col] = acc[mi][ni][j];
      }
}

// =====================================================================
// 6b) reduce partials, scale, softmax -> attnb bf16
// =====================================================================
__global__ __launch_bounds__(256) void attn_softmax(
    const __hip_bfloat16* __restrict__ P, const float* __restrict__ rnorm,
    const float* __restrict__ temp, __hip_bfloat16* __restrict__ attnb)
{
  __shared__ float S[64 * 65];
  const int t = threadIdx.x, h = blockIdx.x, b = blockIdx.y;
  const float* part = (const float*)((const char*)P + (long)b * (CQKV * HW * 2)
                                     + (1024l * HW * 2))
                    + (long)h * NSPLIT * 4096;
  const float tm = temp[h];

  for (int i = t; i < 4096; i += 256) {
    float s = 0.f;
#pragma unroll
    for (int p = 0; p < NSPLIT; ++p) s += part[p * 4096 + i];
    int r = i >> 6, c = i & 63;
    float rq = rnorm[(long)b * 1024 + h * HD + r];
    float rk = rnorm[(long)b * 1024 + 512 + h * HD + c];
    S[r * 65 + c] = s * rq * rk * tm;
  }
  __syncthreads();

  if (t < 64) {
    float m = -3.4e38f;
    for (int e = 0; e < 64; ++e) m = fmaxf(m, S[t * 65 + e]);
    float sum = 0.f;
    for (int e = 0; e < 64; ++e) {
      float ev = __expf(S[t * 65 + e] - m);
      S[t * 65 + e] = ev;
      sum += ev;
    }
    float inv = 1.f / sum;
    for (int e = 0; e < 64; ++e)
      attnb[(((long)b * HEADS + h) * 64 + t) * 64 + e] =
          __float2bfloat16(S[t * 65 + e] * inv);
  }
}

// =====================================================================
// 7) O^T = V^T * attn^T -> OT[b][4096][512] bf16
// =====================================================================
__global__ __launch_bounds__(256) void attn_apply_v(
    const __hip_bfloat16* __restrict__ VT, const __hip_bfloat16* __restrict__ attnb,
    __hip_bfloat16* __restrict__ OT)
{
  __shared__ __hip_bfloat16 ldsV[128 * 64];
  __shared__ __hip_bfloat16 ldsAt[64 * 64];
  const int t = threadIdx.x, w = t >> 6, l = t & 63;
  const int bh = blockIdx.y, b = bh >> 3, h = bh & 7;
  const int n0 = blockIdx.x * 128;

#pragma unroll
  for (int i = 0; i < 4; ++i) {
    int r = w * 32 + i * 8 + (l >> 3);
    int c = (l & 7) ^ (r & 7);
    gload16(VT + ((long)bh * HW + n0 + r) * HD + c * 8, &ldsV[w * 2048 + i * 512]);
  }
#pragma unroll
  for (int i = 0; i < 2; ++i) {
    int r = w * 16 + i * 8 + (l >> 3);
    int c = (l & 7) ^ (r & 7);
    gload16(attnb + ((long)bh * 64 + r) * 64 + c * 8, &ldsAt[w * 1024 + i * 512]);
  }
  __syncthreads();

  f32x4 acc[2][4] = {};
#pragma unroll
  for (int kk = 0; kk < 64; kk += 32) {
    s16x8 af[2], bfr[4];
#pragma unroll
    for (int mi = 0; mi < 2; ++mi) {
      int ar = w * 32 + mi * 16 + (l & 15);
      int col = (kk + (l >> 4) * 8) ^ ((ar & 7) << 3);
      af[mi] = *(const s16x8*)&ldsV[ar * 64 + col];
    }
#pragma unroll
    for (int ni = 0; ni < 4; ++ni) {
      int br = ni * 16 + (l & 15);
      int col = (kk + (l >> 4) * 8) ^ ((br & 7) << 3);
      bfr[ni] = *(const s16x8*)&ldsAt[br * 64 + col];
    }
#pragma unroll
    for (int mi = 0; mi < 2; ++mi)
#pragma unroll
      for (int ni = 0; ni < 4; ++ni)
        acc[mi][ni] = mfma16x32(af[mi], bfr[ni], acc[mi][ni]);
  }

#pragma unroll
  for (int mi = 0; mi < 2; ++mi)
#pragma unroll
    for (int ni = 0; ni < 4; ++ni)
#pragma unroll
      for (int j = 0; j < 4; ++j) {
        long n = n0 + w * 32 + mi * 16 + (l >> 4) * 4 + j;
        long c = h * HD + ni * 16 + (l & 15);
        OT[((long)b * HW + n) * DIM + c] = __float2bfloat16(acc[mi][ni][j]);
      }
}

// =====================================================================
extern "C" void kernel_launch(void* const* d_in, const int* in_sizes, int n_in,
                              void* d_out, int out_size, void* d_ws, size_t ws_size,
                              hipStream_t stream)
{
  const float* x    = (const float*)d_in[0];
  const float* wq   = (const float*)d_in[1];
  const float* wk   = (const float*)d_in[2];
  const float* wv   = (const float*)d_in[3];
  const float* dwq  = (const float*)d_in[4];
  const float* dwk  = (const float*)d_in[5];
  const float* dwv  = (const float*)d_in[6];
  const float* wp   = (const float*)d_in[7];
  const float* temp = (const float*)d_in[8];
  float* out = (float*)d_out;

  char* ws = (char*)d_ws;
  __hip_bfloat16* wqkv  = (__hip_bfloat16*)(ws + 0);                 // 1.5 MB
  __hip_bfloat16* wpb   = (__hip_bfloat16*)(ws + 1572864);           // 0.5 MB
  float*          rnorm = (float*)(ws + 2097152);                    // 32 KB
  __hip_bfloat16* attnb = (__hip_bfloat16*)(ws + 2129920);           // 512 KB
  __hip_bfloat16* XT    = (__hip_bfloat16*)(ws + (4l << 20));        // 32 MB (VT aliases)
  __hip_bfloat16* VT    = XT;
  __hip_bfloat16* P     = (__hip_bfloat16*)(ws + (40l << 20));       // 96 MB (OT aliases)
  __hip_bfloat16* OT    = P;

  trx_prep<<<dim3(64, 8, 9), 256, 0, stream>>>(x, XT, wq, wk, wv, wp, wqkv, wpb);
  // P[b][1536][4096] = Wqkv * XT^T  (128x128 2-phase, T1 XCD swizzle)
  gemm_bt<<<3072, 256, 0, stream>>>(
      wqkv, XT, P, 32, 12, DIM, 3072, HW, (long)HW * DIM, (long)CQKV * HW);
  dwconv<<<dim3(1536, 8), 256, 0, stream>>>(P, dwq, dwk, dwv, rnorm);
  transpose_v<<<dim3(64, 8, 8), 256, 0, stream>>>(P, VT);
  attn_partial<<<dim3(NSPLIT, 8, 8), 256, 0, stream>>>(P);
  attn_softmax<<<dim3(8, 8), 256, 0, stream>>>(P, rnorm, temp, attnb);
  attn_apply_v<<<dim3(32, 64), 256, 0, stream>>>(VT, attnb, OT);
  // out[b][512][4096] = Wp * OT^T  (fp32 out, 8-phase, T1 XCD swizzle)
  gemm_bt8<<<256, 512, 0, stream>>>(
      wpb, OT, out, 16, 2, DIM, 256, HW, (long)HW * DIM, (long)DIM * HW);
}

// Round 11
// 190.794 us; speedup vs baseline: 1.0304x; 1.0304x over previous
//
#include <hip/hip_runtime.h>
#include <hip/hip_bf16.h>
#include <stdint.h>

#define DEV __device__ __forceinline__

typedef __attribute__((ext_vector_type(8))) short   s16x8;
typedef __attribute__((ext_vector_type(8))) __bf16  bf16x8;
typedef __attribute__((ext_vector_type(4))) float   f32x4;

static constexpr int BATCH = 8;
static constexpr int DIM   = 512;
static constexpr int HEADS = 8;
static constexpr int HD    = 64;
static constexpr int HW    = 4096;
static constexpr int CQKV  = 1536;
static constexpr int NSPLIT = 8;

DEV void gload16(const void* g, void* l) {
  __builtin_amdgcn_global_load_lds(
      (const __attribute__((address_space(1))) void*)g,
      (__attribute__((address_space(3))) void*)l,
      16, 0, 0);
}

DEV f32x4 mfma16x32(s16x8 a, s16x8 b, f32x4 c) {
  return __builtin_amdgcn_mfma_f32_16x16x32_bf16(
      __builtin_bit_cast(bf16x8, a), __builtin_bit_cast(bf16x8, b), c, 0, 0, 0);
}

DEV float b2f(short x) {
  unsigned u = (unsigned)(unsigned short)x << 16;
  return __uint_as_float(u);
}
DEV short f2b(float f) { return __builtin_bit_cast(short, __float2bfloat16(f)); }

// =====================================================================
// 1) MERGED: transpose_x (z<8) + weight convert (z==8)
// =====================================================================
__global__ __launch_bounds__(256) void trx_prep(
    const float* __restrict__ x, __hip_bfloat16* __restrict__ XT,
    const float* __restrict__ wq, const float* __restrict__ wk,
    const float* __restrict__ wv, const float* __restrict__ wp,
    __hip_bfloat16* __restrict__ wqkv, __hip_bfloat16* __restrict__ wpb)
{
  const int t = threadIdx.x;
  if (blockIdx.z == 8) {
    long i0 = (((long)blockIdx.y * 64 + blockIdx.x) * 256 + t) * 8;
    const float* src;
    __hip_bfloat16* dst;
    long off;
    if (i0 < (long)CQKV * DIM) {
      int r = (int)(i0 >> 9);
      src = (r < 512) ? wq : (r < 1024) ? wk : wv;
      off = (long)(r & 511) * DIM + (i0 & 511);
      dst = wqkv + i0;
    } else {
      long j0 = i0 - (long)CQKV * DIM;
      src = wp; off = j0; dst = wpb + j0;
    }
    float4 a = *(const float4*)&src[off];
    float4 b = *(const float4*)&src[off + 4];
    s16x8 v;
    v[0] = f2b(a.x); v[1] = f2b(a.y); v[2] = f2b(a.z); v[3] = f2b(a.w);
    v[4] = f2b(b.x); v[5] = f2b(b.y); v[6] = f2b(b.z); v[7] = f2b(b.w);
    *(s16x8*)dst = v;
    return;
  }
  __shared__ float tile[64 * 65];
  const int n0 = blockIdx.x * 64, c0 = blockIdx.y * 64, b = blockIdx.z;
#pragma unroll
  for (int i = 0; i < 16; ++i) {
    int f = i * 256 + t; int ci = f >> 6, nj = f & 63;
    tile[ci * 65 + nj] = x[((long)b * DIM + c0 + ci) * HW + n0 + nj];
  }
  __syncthreads();
#pragma unroll
  for (int i = 0; i < 16; ++i) {
    int f = i * 256 + t; int ni = f >> 6, cj = f & 63;
    XT[((long)b * HW + n0 + ni) * DIM + c0 + cj] = __float2bfloat16(tile[cj * 65 + ni]);
  }
}

// =====================================================================
// 3) gemm_bt: 2-phase 128x128, BK=64, T2-swizzled LDS, plain epilogue.
//    R1-proven 69.6us; default dispatch order (T1 swizzle hurts: R10
//    showed FETCH 36->102 MB because remapped lids spread resident
//    blocks over all 8 batches -> L3 thrash).
// =====================================================================
__global__ __launch_bounds__(256) void gemm_bt(
    const __hip_bfloat16* __restrict__ A,
    const __hip_bfloat16* __restrict__ Bt,
    __hip_bfloat16* __restrict__ Cout,
    int M, int N, int K, long bt_bstride, long c_bstride)
{
  __shared__ __hip_bfloat16 ldsA[128 * 64];
  __shared__ __hip_bfloat16 ldsB[128 * 64];
  const int t = threadIdx.x, w = t >> 6, l = t & 63;
  const int m0 = blockIdx.y * 128, n0 = blockIdx.x * 128, b = blockIdx.z;
  const int wr = w >> 1, wc = w & 1;
  const __hip_bfloat16* Bb = Bt + (long)b * bt_bstride;

  f32x4 acc[4][4] = {};

  for (int k0 = 0; k0 < K; k0 += 64) {
#pragma unroll
    for (int i = 0; i < 4; ++i) {
      int r = w * 32 + i * 8 + (l >> 3);
      int c = (l & 7) ^ (r & 7);
      gload16(A  + (long)(m0 + r) * K + k0 + c * 8, &ldsA[w * 2048 + i * 512]);
      gload16(Bb + (long)(n0 + r) * K + k0 + c * 8, &ldsB[w * 2048 + i * 512]);
    }
    __syncthreads();
#pragma unroll
    for (int kk = 0; kk < 64; kk += 32) {
      s16x8 af[4], bfr[4];
#pragma unroll
      for (int mi = 0; mi < 4; ++mi) {
        int ar = wr * 64 + mi * 16 + (l & 15);
        int col = (kk + (l >> 4) * 8) ^ ((ar & 7) << 3);
        af[mi] = *(const s16x8*)&ldsA[ar * 64 + col];
      }
#pragma unroll
      for (int ni = 0; ni < 4; ++ni) {
        int br = wc * 64 + ni * 16 + (l & 15);
        int col = (kk + (l >> 4) * 8) ^ ((br & 7) << 3);
        bfr[ni] = *(const s16x8*)&ldsB[br * 64 + col];
      }
#pragma unroll
      for (int mi = 0; mi < 4; ++mi)
#pragma unroll
        for (int ni = 0; ni < 4; ++ni)
          acc[mi][ni] = mfma16x32(af[mi], bfr[ni], acc[mi][ni]);
    }
    __syncthreads();
  }

  const int row0 = m0 + wr * 64, col0 = n0 + wc * 64;
#pragma unroll
  for (int mi = 0; mi < 4; ++mi)
#pragma unroll
    for (int ni = 0; ni < 4; ++ni)
#pragma unroll
      for (int j = 0; j < 4; ++j) {
        long rr = row0 + mi * 16 + (l >> 4) * 4 + j;
        long cc = col0 + ni * 16 + (l & 15);
        Cout[(long)b * c_bstride + rr * N + cc] = __float2bfloat16(acc[mi][ni][j]);
      }
}

// =====================================================================
// 3b) gemm_bt8: 256x256 8-phase (proj, fp32 out), default dispatch order
// =====================================================================
__global__ __launch_bounds__(512, 2) void gemm_bt8(
    const __hip_bfloat16* __restrict__ A,
    const __hip_bfloat16* __restrict__ Bt,
    float* __restrict__ Cout,
    int M, int N, int K, long bt_bstride, long c_bstride)
{
  __shared__ __hip_bfloat16 lds[65536];
  const int t = threadIdx.x, w = t >> 6, l = t & 63;
  const int wm = w >> 2, wn = w & 3;
  const int m0 = blockIdx.y * 256, n0 = blockIdx.x * 256, b = blockIdx.z;
  const __hip_bfloat16* Bb = Bt + (long)b * bt_bstride;

  const int rl = t >> 3;
  const int ch = ((t & 7) ^ (rl & 7)) * 8;
  const int fr = l & 15, fk = (l >> 4) * 8;
  const int fswz = (l & 7) << 3;

  auto stageA = [&](int p, int h, int u) {
    const __hip_bfloat16* src = A + (long)(m0 + h * 64 + rl) * K + u * 64 + ch;
    __hip_bfloat16* dst = lds + p * 16384 + h * 8192 + w * 512;
    gload16(src, dst);
    gload16(src + 128l * K, dst + 4096);
  };
  auto stageB = [&](int p, int hb, int u) {
    const __hip_bfloat16* src = Bb + (long)(n0 + hb * 128 + rl) * K + u * 64 + ch;
    __hip_bfloat16* dst = lds + 32768 + p * 16384 + hb * 8192 + w * 512;
    gload16(src, dst);
    gload16(src + 64l * K, dst + 4096);
  };

  f32x4 acc[8][4] = {};
  const int NT = K >> 6;

  stageB(0, 0, 0); stageB(0, 1, 0); stageA(0, 0, 0); stageA(0, 1, 0);
  stageB(1, 0, 1); stageB(1, 1, 1); stageA(1, 0, 1);
  asm volatile("s_waitcnt vmcnt(6)" ::: "memory");
  __builtin_amdgcn_s_barrier();

  for (int u = 0; u < NT; ++u) {
    const int p = u & 1;
    const __hip_bfloat16* lA = lds + p * 16384 + wm * 4096;
    const __hip_bfloat16* lB = lds + 32768 + p * 16384 + (wn >> 1) * 8192
                             + (wn & 1) * 4096;
    s16x8 bfr[2][4];
#pragma unroll
    for (int q = 0; q < 4; ++q) {
      s16x8 afr[2][2];
#pragma unroll
      for (int kk = 0; kk < 2; ++kk)
#pragma unroll
        for (int mi = 0; mi < 2; ++mi)
          afr[kk][mi] = *(const s16x8*)&lA[(q >> 1) * 8192
              + ((q & 1) * 32 + mi * 16 + fr) * 64 + ((kk * 32 + fk) ^ fswz)];
      if (q == 0) {
#pragma unroll
        for (int kk = 0; kk < 2; ++kk)
#pragma unroll
          for (int ni = 0; ni < 4; ++ni)
            bfr[kk][ni] = *(const s16x8*)&lB[(ni * 16 + fr) * 64
                + ((kk * 32 + fk) ^ fswz)];
      }
      if (q == 0)      { if (u + 1 < NT) stageA(p ^ 1, 1, u + 1); }
      else if (q == 1) { if (u + 2 < NT) stageB(p, 0, u + 2); }
      else if (q == 2) { if (u + 2 < NT) stageB(p, 1, u + 2); }
      else {
        if (u + 2 < NT) stageA(p, 0, u + 2);
        if (u == NT - 2) asm volatile("s_waitcnt vmcnt(0)" ::: "memory");
        else             asm volatile("s_waitcnt vmcnt(6)" ::: "memory");
      }
      __builtin_amdgcn_s_barrier();
      asm volatile("s_waitcnt lgkmcnt(0)" ::: "memory");
      __builtin_amdgcn_sched_barrier(0);
      __builtin_amdgcn_s_setprio(1);
#pragma unroll
      for (int kk = 0; kk < 2; ++kk)
#pragma unroll
        for (int mi = 0; mi < 2; ++mi)
#pragma unroll
          for (int ni = 0; ni < 4; ++ni)
            acc[q * 2 + mi][ni] = mfma16x32(afr[kk][mi], bfr[kk][ni],
                                            acc[q * 2 + mi][ni]);
      __builtin_amdgcn_s_setprio(0);
      __builtin_amdgcn_s_barrier();
    }
  }

  const int row0 = m0 + wm * 128, col0 = n0 + wn * 64;
#pragma unroll
  for (int mi = 0; mi < 8; ++mi)
#pragma unroll
    for (int ni = 0; ni < 4; ++ni)
#pragma unroll
      for (int j = 0; j < 4; ++j) {
        long rr = row0 + mi * 16 + (l >> 4) * 4 + j;
        long cc = col0 + ni * 16 + fr;
        Cout[(long)b * c_bstride + rr * N + cc] = acc[mi][ni][j];
      }
}

// =====================================================================
// 4) depthwise 3x3, IN-PLACE on P; q/k emit rnorm
// =====================================================================
__global__ __launch_bounds__(256) void dwconv(
    __hip_bfloat16* __restrict__ P,
    const float* __restrict__ dwq, const float* __restrict__ dwk,
    const float* __restrict__ dwv, float* __restrict__ rnorm)
{
  __shared__ float pl[66 * 67];
  __shared__ float red4[4];
  const int c = blockIdx.x, b = blockIdx.y, t = threadIdx.x;
  const int w = t >> 6, l = t & 63;

  if (t < 66) { pl[t] = 0.f; pl[65 * 67 + t] = 0.f; }
  if (t >= 128 && t < 192) { pl[(t - 127) * 67] = 0.f; }
  if (t >= 192)            { pl[(t - 191) * 67 + 65] = 0.f; }

  const long base = ((long)b * CQKV + c) * HW;
  const int y = t >> 2, x0 = (t & 3) * 16;
  s16x8 v0 = *(const s16x8*)&P[base + t * 16];
  s16x8 v1 = *(const s16x8*)&P[base + t * 16 + 8];
#pragma unroll
  for (int j = 0; j < 8; ++j) {
    pl[(y + 1) * 67 + x0 + 1 + j] = b2f(v0[j]);
    pl[(y + 1) * 67 + x0 + 9 + j] = b2f(v1[j]);
  }
  __syncthreads();

  const int qkv = c >> 9, cc = c & 511;
  const float* dw = ((qkv == 0) ? dwq : (qkv == 1) ? dwk : dwv) + (long)cc * 9;
  const float w0 = dw[0], w1 = dw[1], w2 = dw[2], w3 = dw[3], w4 = dw[4],
              w5 = dw[5], w6 = dw[6], w7 = dw[7], w8 = dw[8];

  const float* r0 = &pl[y * 67 + x0];
  float outv[16];
  float ss = 0.f;
#pragma unroll
  for (int j = 0; j < 16; ++j) {
    float s = w0 * r0[j]       + w1 * r0[j + 1]   + w2 * r0[j + 2]
            + w3 * r0[j + 67]  + w4 * r0[j + 68]  + w5 * r0[j + 69]
            + w6 * r0[j + 134] + w7 * r0[j + 135] + w8 * r0[j + 136];
    outv[j] = s;
    ss += s * s;
  }
  s16x8 o0, o1;
#pragma unroll
  for (int j = 0; j < 8; ++j) { o0[j] = f2b(outv[j]); o1[j] = f2b(outv[j + 8]); }
  *(s16x8*)&P[base + t * 16]     = o0;
  *(s16x8*)&P[base + t * 16 + 8] = o1;

  if (qkv < 2) {
#pragma unroll
    for (int off = 32; off; off >>= 1) ss += __shfl_down(ss, off);
    if (l == 0) red4[w] = ss;
    __syncthreads();
    if (t == 0)
      rnorm[(long)b * 1024 + qkv * 512 + cc] =
          1.f / fmaxf(sqrtf(red4[0] + red4[1] + red4[2] + red4[3]), 1e-12f);
  }
}

// =====================================================================
// 5) V slice of P -> VT [b][h][4096][64] bf16
// =====================================================================
__global__ __launch_bounds__(256) void transpose_v(
    const __hip_bfloat16* __restrict__ P, __hip_bfloat16* __restrict__ VT)
{
  __shared__ __hip_bfloat16 tile[64 * 65];
  const int n0 = blockIdx.x * 64, h = blockIdx.y, b = blockIdx.z;
  const int t = threadIdx.x;
#pragma unroll
  for (int i = 0; i < 16; ++i) {
    int f = i * 256 + t; int ei = f >> 6, nj = f & 63;
    tile[ei * 65 + nj] = P[((long)b * CQKV + 1024 + h * HD + ei) * HW + n0 + nj];
  }
  __syncthreads();
#pragma unroll
  for (int i = 0; i < 16; ++i) {
    int f = i * 256 + t; int ni = f >> 6, ej = f & 63;
    VT[(((long)b * HEADS + h) * HW + n0 + ni) * HD + ej] = tile[ej * 65 + ni];
  }
}

// =====================================================================
// 6a) attention score partials, split-K over hw
// =====================================================================
__global__ __launch_bounds__(256) void attn_partial(__hip_bfloat16* __restrict__ P)
{
  __shared__ __hip_bfloat16 ldsQ[64 * 128];
  __shared__ __hip_bfloat16 ldsK[64 * 128];
  const int t = threadIdx.x, w = t >> 6, l = t & 63;
  const int sp = blockIdx.x, h = blockIdx.y, b = blockIdx.z;
  const int wr = w >> 1, wc = w & 1;

  const long qbase = ((long)b * CQKV + h * HD) * HW;
  const long kbase = ((long)b * CQKV + 512 + h * HD) * HW;

  f32x4 acc[2][2] = {};

  const int kend = sp * 512 + 512;
  for (int k0 = sp * 512; k0 < kend; k0 += 128) {
#pragma unroll
    for (int i = 0; i < 4; ++i) {
      int r = w * 16 + i * 4 + (l >> 4);
      int c = (l & 15) ^ (r & 7);
      gload16(P + qbase + (long)r * HW + k0 + c * 8, &ldsQ[w * 2048 + i * 512]);
      gload16(P + kbase + (long)r * HW + k0 + c * 8, &ldsK[w * 2048 + i * 512]);
    }
    __syncthreads();
#pragma unroll
    for (int kk = 0; kk < 128; kk += 32) {
      s16x8 af[2], bfr[2];
#pragma unroll
      for (int mi = 0; mi < 2; ++mi) {
        int ar = wr * 32 + mi * 16 + (l & 15);
        int col = (kk + (l >> 4) * 8) ^ ((ar & 7) << 3);
        af[mi] = *(const s16x8*)&ldsQ[ar * 128 + col];
      }
#pragma unroll
      for (int ni = 0; ni < 2; ++ni) {
        int br = wc * 32 + ni * 16 + (l & 15);
        int col = (kk + (l >> 4) * 8) ^ ((br & 7) << 3);
        bfr[ni] = *(const s16x8*)&ldsK[br * 128 + col];
      }
#pragma unroll
      for (int mi = 0; mi < 2; ++mi)
#pragma unroll
        for (int ni = 0; ni < 2; ++ni)
          acc[mi][ni] = mfma16x32(af[mi], bfr[ni], acc[mi][ni]);
    }
    __syncthreads();
  }

  float* part = (float*)((char*)P + (long)b * (CQKV * HW * 2) + (1024l * HW * 2))
              + ((long)h * NSPLIT + sp) * 4096;
#pragma unroll
  for (int mi = 0; mi < 2; ++mi)
#pragma unroll
    for (int ni = 0; ni < 2; ++ni)
#pragma unroll
      for (int j = 0; j < 4; ++j) {
        int row = wr * 32 + mi * 16 + (l >> 4) * 4 + j;
        int col = wc * 32 + ni * 16 + (l & 15);
        part[row * 64 + col] = acc[mi][ni][j];
      }
}

// =====================================================================
// 6b) reduce partials, scale, softmax -> attnb bf16
// =====================================================================
__global__ __launch_bounds__(256) void attn_softmax(
    const __hip_bfloat16* __restrict__ P, const float* __restrict__ rnorm,
    const float* __restrict__ temp, __hip_bfloat16* __restrict__ attnb)
{
  __shared__ float S[64 * 65];
  const int t = threadIdx.x, h = blockIdx.x, b = blockIdx.y;
  const float* part = (const float*)((const char*)P + (long)b * (CQKV * HW * 2)
                                     + (1024l * HW * 2))
                    + (long)h * NSPLIT * 4096;
  const float tm = temp[h];

  for (int i = t; i < 4096; i += 256) {
    float s = 0.f;
#pragma unroll
    for (int p = 0; p < NSPLIT; ++p) s += part[p * 4096 + i];
    int r = i >> 6, c = i & 63;
    float rq = rnorm[(long)b * 1024 + h * HD + r];
    float rk = rnorm[(long)b * 1024 + 512 + h * HD + c];
    S[r * 65 + c] = s * rq * rk * tm;
  }
  __syncthreads();

  if (t < 64) {
    float m = -3.4e38f;
    for (int e = 0; e < 64; ++e) m = fmaxf(m, S[t * 65 + e]);
    float sum = 0.f;
    for (int e = 0; e < 64; ++e) {
      float ev = __expf(S[t * 65 + e] - m);
      S[t * 65 + e] = ev;
      sum += ev;
    }
    float inv = 1.f / sum;
    for (int e = 0; e < 64; ++e)
      attnb[(((long)b * HEADS + h) * 64 + t) * 64 + e] =
          __float2bfloat16(S[t * 65 + e] * inv);
  }
}

// =====================================================================
// 7) O^T = V^T * attn^T -> OT[b][4096][512] bf16
// =====================================================================
__global__ __launch_bounds__(256) void attn_apply_v(
    const __hip_bfloat16* __restrict__ VT, const __hip_bfloat16* __restrict__ attnb,
    __hip_bfloat16* __restrict__ OT)
{
  __shared__ __hip_bfloat16 ldsV[128 * 64];
  __shared__ __hip_bfloat16 ldsAt[64 * 64];
  const int t = threadIdx.x, w = t >> 6, l = t & 63;
  const int bh = blockIdx.y, b = bh >> 3, h = bh & 7;
  const int n0 = blockIdx.x * 128;

#pragma unroll
  for (int i = 0; i < 4; ++i) {
    int r = w * 32 + i * 8 + (l >> 3);
    int c = (l & 7) ^ (r & 7);
    gload16(VT + ((long)bh * HW + n0 + r) * HD + c * 8, &ldsV[w * 2048 + i * 512]);
  }
#pragma unroll
  for (int i = 0; i < 2; ++i) {
    int r = w * 16 + i * 8 + (l >> 3);
    int c = (l & 7) ^ (r & 7);
    gload16(attnb + ((long)bh * 64 + r) * 64 + c * 8, &ldsAt[w * 1024 + i * 512]);
  }
  __syncthreads();

  f32x4 acc[2][4] = {};
#pragma unroll
  for (int kk = 0; kk < 64; kk += 32) {
    s16x8 af[2], bfr[4];
#pragma unroll
    for (int mi = 0; mi < 2; ++mi) {
      int ar = w * 32 + mi * 16 + (l & 15);
      int col = (kk + (l >> 4) * 8) ^ ((ar & 7) << 3);
      af[mi] = *(const s16x8*)&ldsV[ar * 64 + col];
    }
#pragma unroll
    for (int ni = 0; ni < 4; ++ni) {
      int br = ni * 16 + (l & 15);
      int col = (kk + (l >> 4) * 8) ^ ((br & 7) << 3);
      bfr[ni] = *(const s16x8*)&ldsAt[br * 64 + col];
    }
#pragma unroll
    for (int mi = 0; mi < 2; ++mi)
#pragma unroll
      for (int ni = 0; ni < 4; ++ni)
        acc[mi][ni] = mfma16x32(af[mi], bfr[ni], acc[mi][ni]);
  }

#pragma unroll
  for (int mi = 0; mi < 2; ++mi)
#pragma unroll
    for (int ni = 0; ni < 4; ++ni)
#pragma unroll
      for (int j = 0; j < 4; ++j) {
        long n = n0 + w * 32 + mi * 16 + (l >> 4) * 4 + j;
        long c = h * HD + ni * 16 + (l & 15);
        OT[((long)b * HW + n) * DIM + c] = __float2bfloat16(acc[mi][ni][j]);
      }
}

// =====================================================================
extern "C" void kernel_launch(void* const* d_in, const int* in_sizes, int n_in,
                              void* d_out, int out_size, void* d_ws, size_t ws_size,
                              hipStream_t stream)
{
  const float* x    = (const float*)d_in[0];
  const float* wq   = (const float*)d_in[1];
  const float* wk   = (const float*)d_in[2];
  const float* wv   = (const float*)d_in[3];
  const float* dwq  = (const float*)d_in[4];
  const float* dwk  = (const float*)d_in[5];
  const float* dwv  = (const float*)d_in[6];
  const float* wp   = (const float*)d_in[7];
  const float* temp = (const float*)d_in[8];
  float* out = (float*)d_out;

  char* ws = (char*)d_ws;
  __hip_bfloat16* wqkv  = (__hip_bfloat16*)(ws + 0);                 // 1.5 MB
  __hip_bfloat16* wpb   = (__hip_bfloat16*)(ws + 1572864);           // 0.5 MB
  float*          rnorm = (float*)(ws + 2097152);                    // 32 KB
  __hip_bfloat16* attnb = (__hip_bfloat16*)(ws + 2129920);           // 512 KB
  __hip_bfloat16* XT    = (__hip_bfloat16*)(ws + (4l << 20));        // 32 MB (VT aliases)
  __hip_bfloat16* VT    = XT;
  __hip_bfloat16* P     = (__hip_bfloat16*)(ws + (40l << 20));       // 96 MB (OT aliases)
  __hip_bfloat16* OT    = P;

  trx_prep<<<dim3(64, 8, 9), 256, 0, stream>>>(x, XT, wq, wk, wv, wp, wqkv, wpb);
  // P[b][1536][4096] = Wqkv * XT^T  (2-phase 128x128, default order)
  gemm_bt<<<dim3(32, 12, 8), 256, 0, stream>>>(
      wqkv, XT, P, CQKV, HW, DIM, (long)HW * DIM, (long)CQKV * HW);
  dwconv<<<dim3(1536, 8), 256, 0, stream>>>(P, dwq, dwk, dwv, rnorm);
  transpose_v<<<dim3(64, 8, 8), 256, 0, stream>>>(P, VT);
  attn_partial<<<dim3(NSPLIT, 8, 8), 256, 0, stream>>>(P);
  attn_softmax<<<dim3(8, 8), 256, 0, stream>>>(P, rnorm, temp, attnb);
  attn_apply_v<<<dim3(32, 64), 256, 0, stream>>>(VT, attnb, OT);
  // out[b][512][4096] = Wp * OT^T  (fp32 out, 8-phase, default order)
  gemm_bt8<<<dim3(16, 2, 8), 512, 0, stream>>>(
      wpb, OT, out, DIM, HW, DIM, (long)HW * DIM, (long)DIM * HW);
}